// Round 1
// baseline (54.478 us; speedup 1.0000x reference)
//
#include <hip/hip_runtime.h>

#define D_DIM 512
#define C_CLS 100

// Kernel 0: gn[c] = ||grp[:, c]||_2  (100 values into d_ws)
__global__ __launch_bounds__(512) void gn_kernel(const float* __restrict__ grp,
                                                 float* __restrict__ gn) {
    __shared__ float red[512];
    const int t = threadIdx.x;
    const int c = t & 127;   // 0..127 (active if < 100)
    const int q = t >> 7;    // 0..3, d-quarter
    float acc = 0.f;
    if (c < C_CLS) {
        const int d0 = q * 128;
        for (int d = d0; d < d0 + 128; ++d) {
            float g = grp[d * C_CLS + c];
            acc = fmaf(g, g, acc);
        }
    }
    red[t] = acc;
    __syncthreads();
    if (t < 128 && c < C_CLS) {
        gn[c] = sqrtf(red[t] + red[t + 128] + red[t + 256] + red[t + 384]);
    }
}

// Main fused kernel: block = 128 threads = 4 samples x 25 class-quads (t<100 active)
__global__ __launch_bounds__(128) void cls_kernel(const float* __restrict__ X,
                                                  const float* __restrict__ grp,
                                                  const float* __restrict__ gn,
                                                  float* __restrict__ out) {
    __shared__ float xs[4][516];   // +4 pad: rows land in distinct banks for ds_read_b128
    __shared__ float redA[4][25];
    __shared__ float redB[4][25];

    const int t = threadIdx.x;
    const int n0 = blockIdx.x * 4;

    // Stage 4 X rows (2048 floats = 512 float4), coalesced
    {
        const float4* Xv = (const float4*)(X + (size_t)n0 * D_DIM);
        for (int i = t; i < 512; i += 128) {
            int row = i >> 7;          // 128 float4 per row
            int col = i & 127;
            *(float4*)&xs[row][col * 4] = Xv[i];
        }
    }
    __syncthreads();

    const int s  = t / 25;             // sample within block (0..3 when active)
    const int cq = t - s * 25;         // class quad (classes 4cq..4cq+3)
    const bool act = (t < 100);

    float l1x = 0.f, l1y = 0.f, l1z = 0.f, l1w = 0.f;
    float dx = 0.f, dy = 0.f, dz = 0.f, dw = 0.f;
    float xsq = 0.f;

    if (act) {
        const float* xrow = xs[s];
        const float* gp = grp + cq * 4;
        for (int d4 = 0; d4 < D_DIM; d4 += 4) {
            float4 xv = *(const float4*)&xrow[d4];
#pragma unroll
            for (int k = 0; k < 4; ++k) {
                float x = (k == 0) ? xv.x : (k == 1) ? xv.y : (k == 2) ? xv.z : xv.w;
                float4 g = *(const float4*)&gp[(d4 + k) * C_CLS];
                l1x += fabsf(x - g.x);  dx = fmaf(x, g.x, dx);
                l1y += fabsf(x - g.y);  dy = fmaf(x, g.y, dy);
                l1z += fabsf(x - g.z);  dz = fmaf(x, g.z, dz);
                l1w += fabsf(x - g.w);  dw = fmaf(x, g.w, dw);
                xsq = fmaf(x, x, xsq);
            }
        }
    }

    float csx = 0.f, csy = 0.f, csz = 0.f, csw = 0.f;
    if (act) {
        float xn = sqrtf(xsq);
        float4 gv = *(const float4*)&gn[cq * 4];
        csx = dx / fmaxf(xn * gv.x, 1e-8f);
        csy = dy / fmaxf(xn * gv.y, 1e-8f);
        csz = dz / fmaxf(xn * gv.z, 1e-8f);
        csw = dw / fmaxf(xn * gv.w, 1e-8f);
        redA[s][cq] = fminf(fminf(l1x, l1y), fminf(l1z, l1w));
        redB[s][cq] = fmaxf(fmaxf(csx, csy), fmaxf(csz, csw));
    }
    __syncthreads();

    float minl1 = 0.f, maxcs = 0.f;
    if (act) {
        minl1 = redA[s][0];
        maxcs = redB[s][0];
        for (int k = 1; k < 25; ++k) {
            minl1 = fminf(minl1, redA[s][k]);
            maxcs = fmaxf(maxcs, redB[s][k]);
        }
    }
    __syncthreads();

    if (act) {
        redA[s][cq] = __expf(minl1 - l1x) + __expf(minl1 - l1y) +
                      __expf(minl1 - l1z) + __expf(minl1 - l1w);
        redB[s][cq] = __expf(csx - maxcs) + __expf(csy - maxcs) +
                      __expf(csz - maxcs) + __expf(csw - maxcs);
    }
    __syncthreads();

    if (act) {
        float s1 = 0.f, s2 = 0.f;
        for (int k = 0; k < 25; ++k) { s1 += redA[s][k]; s2 += redB[s][k]; }
        // out = confidence * softmax(cs) * softmin(l1)
        float f = maxcs / (s1 * s2);
        float4 o;
        o.x = f * __expf(csx - maxcs) * __expf(minl1 - l1x);
        o.y = f * __expf(csy - maxcs) * __expf(minl1 - l1y);
        o.z = f * __expf(csz - maxcs) * __expf(minl1 - l1z);
        o.w = f * __expf(csw - maxcs) * __expf(minl1 - l1w);
        *(float4*)&out[(size_t)(n0 + s) * C_CLS + cq * 4] = o;
    }
}

extern "C" void kernel_launch(void* const* d_in, const int* in_sizes, int n_in,
                              void* d_out, int out_size, void* d_ws, size_t ws_size,
                              hipStream_t stream) {
    const float* X   = (const float*)d_in[0];   // [4096, 512] f32
    const float* grp = (const float*)d_in[1];   // [1, 512, 100] f32
    float* out = (float*)d_out;                 // [4096, 100] f32
    float* gn  = (float*)d_ws;                  // 100 floats scratch

    gn_kernel<<<1, 512, 0, stream>>>(grp, gn);
    cls_kernel<<<1024, 128, 0, stream>>>(X, grp, gn, out);
}

// Round 2
// 36.670 us; speedup vs baseline: 1.4856x; 1.4856x over previous
//
#include <hip/hip_runtime.h>

#define D_DIM 512
#define C_CLS 100
#define SAMP 8     // samples per block
#define NT 256     // threads per block; 200 active = 25 cq * 2 sg * 4 dq

// gn[c] = ||grp[:,c]||  — grid 25 x block 128, block handles 4 classes
__global__ __launch_bounds__(128) void gn_kernel(const float* __restrict__ grp,
                                                 float* __restrict__ gn) {
    __shared__ float4 red[128];
    const int t = threadIdx.x;
    const int cb = blockIdx.x * 4;
    float4 acc = {0.f, 0.f, 0.f, 0.f};
    for (int d = t; d < D_DIM; d += 128) {
        float4 g = *(const float4*)&grp[d * C_CLS + cb];
        acc.x = fmaf(g.x, g.x, acc.x);
        acc.y = fmaf(g.y, g.y, acc.y);
        acc.z = fmaf(g.z, g.z, acc.z);
        acc.w = fmaf(g.w, g.w, acc.w);
    }
    red[t] = acc;
    __syncthreads();
    for (int off = 64; off > 0; off >>= 1) {
        if (t < off) {
            float4 a = red[t], b = red[t + off];
            a.x += b.x; a.y += b.y; a.z += b.z; a.w += b.w;
            red[t] = a;
        }
        __syncthreads();
    }
    if (t == 0) {
        float4 a = red[0];
        gn[cb + 0] = sqrtf(a.x);
        gn[cb + 1] = sqrtf(a.y);
        gn[cb + 2] = sqrtf(a.z);
        gn[cb + 3] = sqrtf(a.w);
    }
}

// Fused: block = 8 samples x 100 classes, D split 4-way across threads.
// Active thread t<200: dq=t/50, sg=(t%50)/25, cq=t%25.
// Micro-tile per thread: 4 samples x 4 classes over 128 d-values.
__global__ __launch_bounds__(NT) void cls_kernel(const float* __restrict__ X,
                                                 const float* __restrict__ grp,
                                                 const float* __restrict__ gn,
                                                 float* __restrict__ out) {
    __shared__ float xs[SAMP][520];          // pad 512->520: rows stay 16B-aligned
    __shared__ float part[4][2][25][36];     // [dq][sg][cq][16 l1 | 16 dot | 4 xsq]
    __shared__ float redA[SAMP][25];
    __shared__ float redB[SAMP][25];

    const int t = threadIdx.x;
    const int n0 = blockIdx.x * SAMP;

    // Stage 8 X rows (4096 floats = 1024 float4), coalesced
    {
        const float4* Xv = (const float4*)(X + (size_t)n0 * D_DIM);
        for (int i = t; i < SAMP * D_DIM / 4; i += NT) {
            int row = i >> 7;
            int col = i & 127;
            *(float4*)&xs[row][col * 4] = Xv[i];
        }
    }
    __syncthreads();

    const bool act = (t < 200);
    int dq = 0, sg = 0, cq = 0;
    if (act) { dq = t / 50; int r = t % 50; sg = r / 25; cq = r % 25; }

    float l1[4][4];
    float dt[4][4];
    float xq[4];
#pragma unroll
    for (int i = 0; i < 4; ++i) {
        xq[i] = 0.f;
#pragma unroll
        for (int j = 0; j < 4; ++j) { l1[i][j] = 0.f; dt[i][j] = 0.f; }
    }

    if (act) {
        const float* gp = grp + cq * 4;
        const int dbase = dq * 128;
        for (int dd = 0; dd < 128; dd += 4) {
            const int d4 = dbase + dd;
            float xr[4][4];   // [si][k], filled by float4 reads, const-indexed after unroll
#pragma unroll
            for (int si = 0; si < 4; ++si)
                *(float4*)&xr[si][0] = *(const float4*)&xs[sg * 4 + si][d4];
#pragma unroll
            for (int k = 0; k < 4; ++k) {
                float4 g = *(const float4*)&gp[(d4 + k) * C_CLS];
                float ga[4] = {g.x, g.y, g.z, g.w};
#pragma unroll
                for (int si = 0; si < 4; ++si) {
                    float x = xr[si][k];
                    xq[si] = fmaf(x, x, xq[si]);
#pragma unroll
                    for (int c = 0; c < 4; ++c) {
                        l1[si][c] += fabsf(x - ga[c]);
                        dt[si][c] = fmaf(x, ga[c], dt[si][c]);
                    }
                }
            }
        }
        // write partials: 16 l1, 16 dot, 4 xsq (9 float4 stores)
        float* p = &part[dq][sg][cq][0];
#pragma unroll
        for (int si = 0; si < 4; ++si) {
            *(float4*)&p[si * 4]      = *(float4*)&l1[si][0];
            *(float4*)&p[16 + si * 4] = *(float4*)&dt[si][0];
        }
        *(float4*)&p[32] = *(float4*)&xq[0];
    }
    __syncthreads();

    // Phase 2: thread (s = t/25 in 0..7, cq = t%25) combines 4 dq partials
    const int s  = t / 25;
    const int c2 = t - s * 25;
    const bool act2 = (t < 200);

    float l1c[4] = {0.f, 0.f, 0.f, 0.f};
    float dtc[4] = {0.f, 0.f, 0.f, 0.f};
    float xsq = 0.f;
    if (act2) {
        const int sg2 = s >> 2, si2 = s & 3;
#pragma unroll
        for (int q = 0; q < 4; ++q) {
            const float* p = &part[q][sg2][c2][0];
            float4 a = *(const float4*)&p[si2 * 4];
            float4 b = *(const float4*)&p[16 + si2 * 4];
            l1c[0] += a.x; l1c[1] += a.y; l1c[2] += a.z; l1c[3] += a.w;
            dtc[0] += b.x; dtc[1] += b.y; dtc[2] += b.z; dtc[3] += b.w;
            xsq += p[32 + si2];
        }
    }

    float cs[4] = {0.f, 0.f, 0.f, 0.f};
    if (act2) {
        float xn = sqrtf(xsq);
        float4 gv = *(const float4*)&gn[c2 * 4];
        cs[0] = dtc[0] / fmaxf(xn * gv.x, 1e-8f);
        cs[1] = dtc[1] / fmaxf(xn * gv.y, 1e-8f);
        cs[2] = dtc[2] / fmaxf(xn * gv.z, 1e-8f);
        cs[3] = dtc[3] / fmaxf(xn * gv.w, 1e-8f);
        redA[s][c2] = fminf(fminf(l1c[0], l1c[1]), fminf(l1c[2], l1c[3]));
        redB[s][c2] = fmaxf(fmaxf(cs[0], cs[1]), fmaxf(cs[2], cs[3]));
    }
    __syncthreads();

    float minl1 = 0.f, maxcs = 0.f;
    if (act2) {
        minl1 = redA[s][0];
        maxcs = redB[s][0];
        for (int k = 1; k < 25; ++k) {
            minl1 = fminf(minl1, redA[s][k]);
            maxcs = fmaxf(maxcs, redB[s][k]);
        }
    }
    __syncthreads();

    if (act2) {
        redA[s][c2] = __expf(minl1 - l1c[0]) + __expf(minl1 - l1c[1]) +
                      __expf(minl1 - l1c[2]) + __expf(minl1 - l1c[3]);
        redB[s][c2] = __expf(cs[0] - maxcs) + __expf(cs[1] - maxcs) +
                      __expf(cs[2] - maxcs) + __expf(cs[3] - maxcs);
    }
    __syncthreads();

    if (act2) {
        float s1 = 0.f, s2 = 0.f;
        for (int k = 0; k < 25; ++k) { s1 += redA[s][k]; s2 += redB[s][k]; }
        float f = maxcs / (s1 * s2);
        float4 o;
        o.x = f * __expf(cs[0] - maxcs) * __expf(minl1 - l1c[0]);
        o.y = f * __expf(cs[1] - maxcs) * __expf(minl1 - l1c[1]);
        o.z = f * __expf(cs[2] - maxcs) * __expf(minl1 - l1c[2]);
        o.w = f * __expf(cs[3] - maxcs) * __expf(minl1 - l1c[3]);
        *(float4*)&out[(size_t)(n0 + s) * C_CLS + c2 * 4] = o;
    }
}

extern "C" void kernel_launch(void* const* d_in, const int* in_sizes, int n_in,
                              void* d_out, int out_size, void* d_ws, size_t ws_size,
                              hipStream_t stream) {
    const float* X   = (const float*)d_in[0];   // [4096, 512] f32
    const float* grp = (const float*)d_in[1];   // [1, 512, 100] f32
    float* out = (float*)d_out;                 // [4096, 100] f32
    float* gn  = (float*)d_ws;                  // 100 floats scratch

    gn_kernel<<<25, 128, 0, stream>>>(grp, gn);
    cls_kernel<<<4096 / SAMP, NT, 0, stream>>>(X, grp, gn, out);
}

// Round 3
// 35.906 us; speedup vs baseline: 1.5172x; 1.0213x over previous
//
#include <hip/hip_runtime.h>

#define D_DIM 512
#define C_CLS 100
#define SAMP 4     // samples per block
#define NT 256     // threads; 200 active = 8 dq * 25 cq

// gn[c] = ||grp[:,c]||  — grid 25 x block 128, block handles 4 classes
__global__ __launch_bounds__(128) void gn_kernel(const float* __restrict__ grp,
                                                 float* __restrict__ gn) {
    __shared__ float4 red[128];
    const int t = threadIdx.x;
    const int cb = blockIdx.x * 4;
    float4 acc = {0.f, 0.f, 0.f, 0.f};
    for (int d = t; d < D_DIM; d += 128) {
        float4 g = *(const float4*)&grp[d * C_CLS + cb];
        acc.x = fmaf(g.x, g.x, acc.x);
        acc.y = fmaf(g.y, g.y, acc.y);
        acc.z = fmaf(g.z, g.z, acc.z);
        acc.w = fmaf(g.w, g.w, acc.w);
    }
    red[t] = acc;
    __syncthreads();
    for (int off = 64; off > 0; off >>= 1) {
        if (t < off) {
            float4 a = red[t], b = red[t + off];
            a.x += b.x; a.y += b.y; a.z += b.z; a.w += b.w;
            red[t] = a;
        }
        __syncthreads();
    }
    if (t == 0) {
        float4 a = red[0];
        gn[cb + 0] = sqrtf(a.x);
        gn[cb + 1] = sqrtf(a.y);
        gn[cb + 2] = sqrtf(a.z);
        gn[cb + 3] = sqrtf(a.w);
    }
}

// Fused: block = 4 samples x 100 classes, D split 8-way across threads.
// Active t<200: dq=t/25 (0..7), cq=t%25. Tile: 4 samples x 4 classes x 64 d.
__global__ __launch_bounds__(NT, 4) void cls_kernel(const float* __restrict__ X,
                                                    const float* __restrict__ grp,
                                                    const float* __restrict__ gn,
                                                    float* __restrict__ out) {
    __shared__ float xs[SAMP][520];        // pad keeps rows 16B-aligned, shifts banks
    __shared__ float part[8][25][36];      // [dq][cq][16 l1 | 16 dot | 4 pad]
    __shared__ float redA[SAMP][25];
    __shared__ float redB[SAMP][25];
    __shared__ float xsqs[SAMP];

    const int t = threadIdx.x;
    const int n0 = blockIdx.x * SAMP;

    // Stage 4 X rows (2048 floats = 512 float4), coalesced: 2 per thread
    {
        const float4* Xv = (const float4*)(X + (size_t)n0 * D_DIM);
#pragma unroll
        for (int i = t; i < SAMP * D_DIM / 4; i += NT) {
            int row = i >> 7;
            int col = i & 127;
            *(float4*)&xs[row][col * 4] = Xv[i];
        }
    }
    __syncthreads();

    // ||x||^2 per row: threads 0..127, 32 threads/row, shuffle-reduce
    if (t < 128) {
        const int r = t >> 5, j = t & 31;
        float v = 0.f;
#pragma unroll
        for (int k = 0; k < 4; ++k) {
            float4 a = *(const float4*)&xs[r][j * 4 + k * 128];
            v += a.x * a.x + a.y * a.y + a.z * a.z + a.w * a.w;
        }
#pragma unroll
        for (int m = 16; m > 0; m >>= 1) v += __shfl_xor(v, m, 32);
        if (j == 0) xsqs[r] = v;
    }

    const bool act = (t < 200);
    const int dq = t / 25;
    const int cq = t - dq * 25;

    float l1[4][4];
    float dt[4][4];
#pragma unroll
    for (int i = 0; i < 4; ++i)
#pragma unroll
        for (int j = 0; j < 4; ++j) { l1[i][j] = 0.f; dt[i][j] = 0.f; }

    if (act) {
        const float* gp = grp + cq * 4;
        const int dbase = dq * 64;
#pragma unroll 4
        for (int dd = 0; dd < 64; dd += 4) {
            const int d4 = dbase + dd;
            float xr[4][4];   // [si][k]
#pragma unroll
            for (int si = 0; si < 4; ++si)
                *(float4*)&xr[si][0] = *(const float4*)&xs[si][d4];
#pragma unroll
            for (int k = 0; k < 4; ++k) {
                float4 g = *(const float4*)&gp[(d4 + k) * C_CLS];
                float ga[4] = {g.x, g.y, g.z, g.w};
#pragma unroll
                for (int si = 0; si < 4; ++si) {
                    float x = xr[si][k];
#pragma unroll
                    for (int c = 0; c < 4; ++c) {
                        l1[si][c] += fabsf(x - ga[c]);
                        dt[si][c] = fmaf(x, ga[c], dt[si][c]);
                    }
                }
            }
        }
        float* p = &part[dq][cq][0];
#pragma unroll
        for (int si = 0; si < 4; ++si) {
            *(float4*)&p[si * 4]      = *(float4*)&l1[si][0];
            *(float4*)&p[16 + si * 4] = *(float4*)&dt[si][0];
        }
    }
    __syncthreads();

    // Phase 2: thread (s = t/25 in 0..3, c2 = t%25) combines 8 dq partials
    const int s  = t / 25;
    const int c2 = t - s * 25;
    const bool act2 = (t < 100);

    float l1c[4] = {0.f, 0.f, 0.f, 0.f};
    float dtc[4] = {0.f, 0.f, 0.f, 0.f};
    if (act2) {
#pragma unroll
        for (int q = 0; q < 8; ++q) {
            const float* p = &part[q][c2][0];
            float4 a = *(const float4*)&p[s * 4];
            float4 b = *(const float4*)&p[16 + s * 4];
            l1c[0] += a.x; l1c[1] += a.y; l1c[2] += a.z; l1c[3] += a.w;
            dtc[0] += b.x; dtc[1] += b.y; dtc[2] += b.z; dtc[3] += b.w;
        }
    }

    float cs[4] = {0.f, 0.f, 0.f, 0.f};
    if (act2) {
        float xn = sqrtf(xsqs[s]);
        float4 gv = *(const float4*)&gn[c2 * 4];
        cs[0] = dtc[0] / fmaxf(xn * gv.x, 1e-8f);
        cs[1] = dtc[1] / fmaxf(xn * gv.y, 1e-8f);
        cs[2] = dtc[2] / fmaxf(xn * gv.z, 1e-8f);
        cs[3] = dtc[3] / fmaxf(xn * gv.w, 1e-8f);
        redA[s][c2] = fminf(fminf(l1c[0], l1c[1]), fminf(l1c[2], l1c[3]));
        redB[s][c2] = fmaxf(fmaxf(cs[0], cs[1]), fmaxf(cs[2], cs[3]));
    }
    __syncthreads();

    float minl1 = 0.f, maxcs = 0.f;
    if (act2) {
        minl1 = redA[s][0];
        maxcs = redB[s][0];
        for (int k = 1; k < 25; ++k) {
            minl1 = fminf(minl1, redA[s][k]);
            maxcs = fmaxf(maxcs, redB[s][k]);
        }
    }
    __syncthreads();

    if (act2) {
        redA[s][c2] = __expf(minl1 - l1c[0]) + __expf(minl1 - l1c[1]) +
                      __expf(minl1 - l1c[2]) + __expf(minl1 - l1c[3]);
        redB[s][c2] = __expf(cs[0] - maxcs) + __expf(cs[1] - maxcs) +
                      __expf(cs[2] - maxcs) + __expf(cs[3] - maxcs);
    }
    __syncthreads();

    if (act2) {
        float s1 = 0.f, s2 = 0.f;
        for (int k = 0; k < 25; ++k) { s1 += redA[s][k]; s2 += redB[s][k]; }
        float f = maxcs / (s1 * s2);
        float4 o;
        o.x = f * __expf(cs[0] - maxcs) * __expf(minl1 - l1c[0]);
        o.y = f * __expf(cs[1] - maxcs) * __expf(minl1 - l1c[1]);
        o.z = f * __expf(cs[2] - maxcs) * __expf(minl1 - l1c[2]);
        o.w = f * __expf(cs[3] - maxcs) * __expf(minl1 - l1c[3]);
        *(float4*)&out[(size_t)(n0 + s) * C_CLS + c2 * 4] = o;
    }
}

extern "C" void kernel_launch(void* const* d_in, const int* in_sizes, int n_in,
                              void* d_out, int out_size, void* d_ws, size_t ws_size,
                              hipStream_t stream) {
    const float* X   = (const float*)d_in[0];   // [4096, 512] f32
    const float* grp = (const float*)d_in[1];   // [1, 512, 100] f32
    float* out = (float*)d_out;                 // [4096, 100] f32
    float* gn  = (float*)d_ws;                  // 100 floats scratch

    gn_kernel<<<25, 128, 0, stream>>>(grp, gn);
    cls_kernel<<<4096 / SAMP, NT, 0, stream>>>(X, grp, gn, out);
}

// Round 4
// 32.897 us; speedup vs baseline: 1.6560x; 1.0915x over previous
//
#include <hip/hip_runtime.h>

typedef float v2f __attribute__((ext_vector_type(2)));

#define D_DIM 512
#define C_CLS 100
#define SAMP 4     // samples per block
#define NT 256     // threads; 200 active = 8 dq * 25 cq

// Single fused kernel: block = 4 samples x 100 classes, D split 8-way.
// Active t<200: dq=t/25 (0..7), cq=t%25. Tile: 4 samples x 4 classes x 64 d.
// Inner math packed over class-pairs (v_pk_add_f32 / v_pk_fma_f32).
// ||g_c||^2 folded into the main loop (no separate gn kernel).
__global__ __launch_bounds__(NT, 4) void cls_kernel(const float* __restrict__ X,
                                                    const float* __restrict__ grp,
                                                    float* __restrict__ out) {
    __shared__ float xs[SAMP][520];        // pad keeps rows 16B-aligned
    __shared__ float part[8][25][36];      // [dq][cq][16 l1 | 16 dot | 4 gsq]
    __shared__ float redA[SAMP][25];
    __shared__ float redB[SAMP][25];
    __shared__ float xsqs[SAMP];

    const int t = threadIdx.x;
    const int n0 = blockIdx.x * SAMP;

    // Stage 4 X rows (2048 floats = 512 float4), coalesced
    {
        const float4* Xv = (const float4*)(X + (size_t)n0 * D_DIM);
#pragma unroll
        for (int i = t; i < SAMP * D_DIM / 4; i += NT) {
            int row = i >> 7;
            int col = i & 127;
            *(float4*)&xs[row][col * 4] = Xv[i];
        }
    }
    __syncthreads();

    // ||x||^2 per row: threads 0..127, 32 threads/row, shuffle-reduce
    if (t < 128) {
        const int r = t >> 5, j = t & 31;
        float v = 0.f;
#pragma unroll
        for (int k = 0; k < 4; ++k) {
            float4 a = *(const float4*)&xs[r][j * 4 + k * 128];
            v += a.x * a.x + a.y * a.y + a.z * a.z + a.w * a.w;
        }
#pragma unroll
        for (int m = 16; m > 0; m >>= 1) v += __shfl_xor(v, m, 32);
        if (j == 0) xsqs[r] = v;
    }

    const bool act = (t < 200);
    const int dq = t / 25;
    const int cq = t - dq * 25;

    float l1[4][4];
    v2f dtl[4], dth[4];                    // dot accum, class-pairs (c0,c1),(c2,c3)
    v2f gsql = {0.f, 0.f}, gsqh = {0.f, 0.f};
#pragma unroll
    for (int i = 0; i < 4; ++i) {
        dtl[i] = (v2f){0.f, 0.f};
        dth[i] = (v2f){0.f, 0.f};
#pragma unroll
        for (int j = 0; j < 4; ++j) l1[i][j] = 0.f;
    }

    if (act) {
        const float* gp = grp + cq * 4;
        const int dbase = dq * 64;
#pragma unroll 2
        for (int dd = 0; dd < 64; dd += 4) {
            const int d4 = dbase + dd;
            float xr[4][4];   // [si][k]
#pragma unroll
            for (int si = 0; si < 4; ++si)
                *(float4*)&xr[si][0] = *(const float4*)&xs[si][d4];
#pragma unroll
            for (int k = 0; k < 4; ++k) {
                float4 g = *(const float4*)&gp[(d4 + k) * C_CLS];
                v2f glo = {g.x, g.y};
                v2f ghi = {g.z, g.w};
                gsql += glo * glo;                 // v_pk_fma_f32
                gsqh += ghi * ghi;
#pragma unroll
                for (int si = 0; si < 4; ++si) {
                    float x = xr[si][k];
                    v2f x2 = {x, x};
                    v2f el = x2 - glo;             // v_pk_add_f32 (neg)
                    v2f eh = x2 - ghi;
                    l1[si][0] += fabsf(el.x);      // v_add_f32 with abs modifier
                    l1[si][1] += fabsf(el.y);
                    l1[si][2] += fabsf(eh.x);
                    l1[si][3] += fabsf(eh.y);
                    dtl[si] += x2 * glo;           // v_pk_fma_f32
                    dth[si] += x2 * ghi;
                }
            }
        }
        float* p = &part[dq][cq][0];
#pragma unroll
        for (int si = 0; si < 4; ++si) {
            *(float4*)&p[si * 4]      = float4{l1[si][0], l1[si][1], l1[si][2], l1[si][3]};
            *(float4*)&p[16 + si * 4] = float4{dtl[si].x, dtl[si].y, dth[si].x, dth[si].y};
        }
        *(float4*)&p[32] = float4{gsql.x, gsql.y, gsqh.x, gsqh.y};
    }
    __syncthreads();

    // Phase 2: thread (s = t/25 in 0..3, c2 = t%25) combines 8 dq partials
    const int s  = t / 25;
    const int c2 = t - s * 25;
    const bool act2 = (t < 100);

    float l1c[4] = {0.f, 0.f, 0.f, 0.f};
    float dtc[4] = {0.f, 0.f, 0.f, 0.f};
    float gsc[4] = {0.f, 0.f, 0.f, 0.f};
    if (act2) {
#pragma unroll
        for (int q = 0; q < 8; ++q) {
            const float* p = &part[q][c2][0];
            float4 a = *(const float4*)&p[s * 4];
            float4 b = *(const float4*)&p[16 + s * 4];
            float4 c = *(const float4*)&p[32];
            l1c[0] += a.x; l1c[1] += a.y; l1c[2] += a.z; l1c[3] += a.w;
            dtc[0] += b.x; dtc[1] += b.y; dtc[2] += b.z; dtc[3] += b.w;
            gsc[0] += c.x; gsc[1] += c.y; gsc[2] += c.z; gsc[3] += c.w;
        }
    }

    float cs[4] = {0.f, 0.f, 0.f, 0.f};
    if (act2) {
        float xq = xsqs[s];
#pragma unroll
        for (int c = 0; c < 4; ++c)
            cs[c] = dtc[c] / fmaxf(sqrtf(xq * gsc[c]), 1e-8f);
        redA[s][c2] = fminf(fminf(l1c[0], l1c[1]), fminf(l1c[2], l1c[3]));
        redB[s][c2] = fmaxf(fmaxf(cs[0], cs[1]), fmaxf(cs[2], cs[3]));
    }
    __syncthreads();

    float minl1 = 0.f, maxcs = 0.f;
    if (act2) {
        minl1 = redA[s][0];
        maxcs = redB[s][0];
        for (int k = 1; k < 25; ++k) {
            minl1 = fminf(minl1, redA[s][k]);
            maxcs = fmaxf(maxcs, redB[s][k]);
        }
    }
    __syncthreads();

    if (act2) {
        redA[s][c2] = __expf(minl1 - l1c[0]) + __expf(minl1 - l1c[1]) +
                      __expf(minl1 - l1c[2]) + __expf(minl1 - l1c[3]);
        redB[s][c2] = __expf(cs[0] - maxcs) + __expf(cs[1] - maxcs) +
                      __expf(cs[2] - maxcs) + __expf(cs[3] - maxcs);
    }
    __syncthreads();

    if (act2) {
        float s1 = 0.f, s2 = 0.f;
        for (int k = 0; k < 25; ++k) { s1 += redA[s][k]; s2 += redB[s][k]; }
        float f = maxcs / (s1 * s2);
        float4 o;
        o.x = f * __expf(cs[0] - maxcs) * __expf(minl1 - l1c[0]);
        o.y = f * __expf(cs[1] - maxcs) * __expf(minl1 - l1c[1]);
        o.z = f * __expf(cs[2] - maxcs) * __expf(minl1 - l1c[2]);
        o.w = f * __expf(cs[3] - maxcs) * __expf(minl1 - l1c[3]);
        *(float4*)&out[(size_t)(n0 + s) * C_CLS + c2 * 4] = o;
    }
}

extern "C" void kernel_launch(void* const* d_in, const int* in_sizes, int n_in,
                              void* d_out, int out_size, void* d_ws, size_t ws_size,
                              hipStream_t stream) {
    const float* X   = (const float*)d_in[0];   // [4096, 512] f32
    const float* grp = (const float*)d_in[1];   // [1, 512, 100] f32
    float* out = (float*)d_out;                 // [4096, 100] f32
    (void)d_ws; (void)ws_size;

    cls_kernel<<<4096 / SAMP, NT, 0, stream>>>(X, grp, out);
}